// Round 7
// baseline (746.497 us; speedup 1.0000x reference)
//
#include <hip/hip_runtime.h>
#include <hip/hip_bf16.h>

typedef short bf16x8 __attribute__((ext_vector_type(8)));
typedef float f32x4 __attribute__((ext_vector_type(4)));
typedef unsigned short u16t;

__device__ __forceinline__ u16t f2bf(float f) {
    return __builtin_bit_cast(u16t, __float2bfloat16(f));   // v_cvt_pk_bf16_f32 pairs
}

__device__ __forceinline__ f32x4 mfma16(bf16x8 a, bf16x8 b, f32x4 c) {
    return __builtin_amdgcn_mfma_f32_16x16x32_bf16(a, b, c, 0, 0, 0);
}

// Expanded transposed weight: wt[n'][k'] = (n'%D==k'%D) ? w[k'/D][n'/D]*scale : 0
template<int D, int MUL>
__global__ void expand_w(const float* __restrict__ w, u16t* __restrict__ wt, float scale) {
    const int n = blockIdx.x;
    const int k = threadIdx.x;
    float v = 0.0f;
    if (D == 1 || (n % D) == (k % D))
        v = w[(k / D) * MUL + (n / D)] * scale;
    wt[n * (MUL * D) + k] = f2bf(v);
}

// One irrep block, 32-row tiles, grid-stride with cross-tile register prefetch.
// 4 waves = 2m x 2n. Chunks = 2 n-tiles (128B) -> every store burst completes a line.
template<int KP, int OFF>
__device__ __forceinline__ void do_block(const float* __restrict__ x,
                                         const u16t* __restrict__ wb,
                                         float* __restrict__ out,
                                         char* smem, int tile0, int tstride,
                                         int ntiles, int tid) {
    constexpr int C8 = KP / 8;        // bf16x8 slots per row
    constexpr int IT = C8 / 8;        // stage iters: 32*C8/256
    constexpr int KS = KP / 32;
    constexpr int NT = KP / 16;
    constexpr int CH = NT / 4;        // chunks (2 nt each) per n-half
    const int lane = tid & 63, wv = tid >> 6, lr = lane & 15, q = lane >> 4;
    const int mg = wv >> 1, ng = wv & 1;

    // ---- initial global loads (held in regs) ----
    f32x4 g[IT * 2];
    #pragma unroll
    for (int it = 0; it < IT; ++it) {
        int idx = tid + it * 256;
        int row = idx / C8, c8 = idx % C8;
        const float* p = x + ((long)tile0 * 32 + row) * 960 + OFF + c8 * 8;
        g[2 * it]     = *(const f32x4*)p;
        g[2 * it + 1] = *(const f32x4*)(p + 4);
    }

    for (int t = tile0; t < ntiles; t += tstride) {
        // ---- cvt + swizzled LDS write (compiler waits on g) ----
        #pragma unroll
        for (int it = 0; it < IT; ++it) {
            int idx = tid + it * 256;
            int row = idx / C8, c8 = idx % C8;
            bf16x8 sv;
            #pragma unroll
            for (int e = 0; e < 4; ++e) {
                sv[e]     = f2bf(g[2 * it][e]);
                sv[e + 4] = f2bf(g[2 * it + 1][e]);
            }
            *(bf16x8*)(smem + row * (KP * 2) + ((c8 * 16) ^ ((row & 7) << 4))) = sv;
        }
        asm volatile("s_waitcnt lgkmcnt(0)" ::: "memory");
        __builtin_amdgcn_s_barrier();

        // ---- prefetch next tile: loads stay in flight through compute ----
        {
            int tn = t + tstride; if (tn >= ntiles) tn = t;
            #pragma unroll
            for (int it = 0; it < IT; ++it) {
                int idx = tid + it * 256;
                int row = idx / C8, c8 = idx % C8;
                const float* p = x + ((long)tn * 32 + row) * 960 + OFF + c8 * 8;
                g[2 * it]     = *(const f32x4*)p;
                g[2 * it + 1] = *(const f32x4*)(p + 4);
            }
        }

        // ---- compute: chunks of 2 nt; acc = 8 VGPR; full-line stores ----
        const char* ar = smem + (mg * 16 + lr) * (KP * 2);
        #pragma unroll
        for (int c = 0; c < CH; ++c) {
            const int ntg = ng * (NT / 2) + c * 2;
            f32x4 acc0 = {0.f, 0.f, 0.f, 0.f}, acc1 = {0.f, 0.f, 0.f, 0.f};
            #pragma unroll
            for (int ks = 0; ks < KS; ++ks) {
                bf16x8 a  = *(const bf16x8*)(ar + ((ks * 64 + q * 16) ^ ((lr & 7) << 4)));
                bf16x8 b0 = *(const bf16x8*)(wb + ((ntg + 0) * 16 + lr) * KP + ks * 32 + q * 8);
                bf16x8 b1 = *(const bf16x8*)(wb + ((ntg + 1) * 16 + lr) * KP + ks * 32 + q * 8);
                acc0 = mfma16(a, b0, acc0);
                acc1 = mfma16(a, b1, acc1);
            }
            float* ow = out + ((long)t * 32 + mg * 16 + q * 4) * 960 + OFF + ntg * 16 + lr;
            #pragma unroll
            for (int j = 0; j < 4; ++j) {   // both 64B halves adjacent -> full 128B line
                ow[j * 960]      = acc0[j];
                ow[j * 960 + 16] = acc1[j];
            }
        }
        __builtin_amdgcn_s_barrier();   // raw: prefetch loads remain in flight
    }
}

// blockIdx % 3 -> mixed block types (and phases) per CU.
__global__ __launch_bounds__(256, 5)
void fused_linear(const float* __restrict__ x, const u16t* __restrict__ wt,
                  float* __restrict__ out, int ntiles) {
    __shared__ __align__(16) char smem[32 * 384 * 2];   // 24 KB (block1 size)
    const int bt = (int)(blockIdx.x % 3);
    const int t0 = (int)(blockIdx.x / 3);
    const int ts = (int)(gridDim.x / 3);
    const int tid = threadIdx.x;
    if (bt == 0)      do_block<256,   0>(x, wt,          out, smem, t0, ts, ntiles, tid);
    else if (bt == 1) do_block<384, 256>(x, wt +  65536, out, smem, t0, ts, ntiles, tid);
    else              do_block<320, 640>(x, wt + 212992, out, smem, t0, ts, ntiles, tid);
}

extern "C" void kernel_launch(void* const* d_in, const int* in_sizes, int n_in,
                              void* d_out, int out_size, void* d_ws, size_t ws_size,
                              hipStream_t stream) {
    const float* x  = (const float*)d_in[0];
    const float* w0 = (const float*)d_in[1];
    const float* w1 = (const float*)d_in[2];
    const float* w2 = (const float*)d_in[3];
    float* out = (float*)d_out;
    u16t* wt = (u16t*)d_ws;   // 616 KB scratch

    const int N      = in_sizes[0] / 960;
    const int ntiles = N / 32;                       // 4096
    const int gs     = (ntiles < 2048 ? ntiles : 2048);

    expand_w<1, 256><<<256, 256, 0, stream>>>(w0, wt,          0.0625f);
    expand_w<3, 128><<<384, 384, 0, stream>>>(w1, wt +  65536, 0.08838834764831845f);
    expand_w<5,  64><<<320, 320, 0, stream>>>(w2, wt + 212992, 0.125f);

    fused_linear<<<3 * gs, 256, 0, stream>>>(x, wt, out, ntiles);
}

// Round 8
// 329.827 us; speedup vs baseline: 2.2633x; 2.2633x over previous
//
#include <hip/hip_runtime.h>
#include <hip/hip_bf16.h>

typedef short bf16x8 __attribute__((ext_vector_type(8)));
typedef short bf16x4 __attribute__((ext_vector_type(4)));
typedef float f32x4 __attribute__((ext_vector_type(4)));
typedef unsigned short u16t;

__device__ __forceinline__ u16t f2bf(float f) {
    return __builtin_bit_cast(u16t, __float2bfloat16(f));
}
__device__ __forceinline__ f32x4 mfma16(bf16x8 a, bf16x8 b, f32x4 c) {
    return __builtin_amdgcn_mfma_f32_16x16x32_bf16(a, b, c, 0, 0, 0);
}

// compact transposed weights: wt[n][k] = w[k][n] * scale  (bf16)
__global__ void convert_w(const float* __restrict__ w, u16t* __restrict__ wt,
                          int mul, float scale) {
    int idx = blockIdx.x * blockDim.x + threadIdx.x;
    if (idx >= mul * mul) return;
    int n = idx / mul, k = idx % mul;
    wt[idx] = f2bf(w[k * mul + n] * scale);
}

// ---------------- type 0: 256x0e, K=256, 32-row tiles ----------------
__device__ void do_t0(const float* __restrict__ x, const u16t* __restrict__ wb,
                      float* __restrict__ out, char* sA,
                      int t0, int ts, int ntiles, int tid) {
    const int row = tid >> 3, jj = tid & 7;           // producer: 32 rows x 8 thr
    const int lane = tid & 63, wv = tid >> 6, lr = lane & 15, q = lane >> 4;
    const int swr = (row & 7) << 4, swl = (lr & 7) << 4;
    const float* gp = x + (long)row * 960 + jj * 32;  // OFF=0, 128B/thread

    f32x4 g[8];
    {   const float* p = gp + (long)t0 * 32 * 960;
        #pragma unroll
        for (int i = 0; i < 8; ++i) g[i] = *(const f32x4*)(p + 4 * i); }
    __builtin_amdgcn_sched_barrier(0);

    int w = 0;
    for (int t = t0; t < ntiles; t += ts, w ^= 1) {
        char* buf = sA + w * 16384;
        #pragma unroll
        for (int h = 0; h < 4; ++h) {                 // 4 x b128 swizzled writes
            bf16x8 v;
            #pragma unroll
            for (int e = 0; e < 4; ++e) {
                v[e]     = f2bf(g[2 * h][e]);
                v[e + 4] = f2bf(g[2 * h + 1][e]);
            }
            *(bf16x8*)(buf + row * 512 + ((jj * 64 + h * 16) ^ swr)) = v;
        }
        if (t + ts < ntiles) {
            const float* p = gp + (long)(t + ts) * 32 * 960;
            #pragma unroll
            for (int i = 0; i < 8; ++i) g[i] = *(const f32x4*)(p + 4 * i);
        }
        __builtin_amdgcn_sched_barrier(0);
        asm volatile("s_waitcnt lgkmcnt(0)" ::: "memory");
        __builtin_amdgcn_s_barrier();
        __builtin_amdgcn_sched_barrier(0);

        f32x4 acc[2][4] = {};
        const u16t* wq = wb + lr * 256 + q * 8;
        #pragma unroll
        for (int ks = 0; ks < 8; ++ks) {
            bf16x8 b[4];
            #pragma unroll
            for (int i = 0; i < 4; ++i)
                b[i] = *(const bf16x8*)(wq + (wv * 4 + i) * 4096 + ks * 32);
            #pragma unroll
            for (int mt = 0; mt < 2; ++mt) {
                bf16x8 a = *(const bf16x8*)(buf + (mt * 16 + lr) * 512 +
                                            ((ks * 64 + q * 16) ^ swl));
                #pragma unroll
                for (int i = 0; i < 4; ++i)
                    acc[mt][i] = mfma16(a, b[i], acc[mt][i]);
            }
        }
        #pragma unroll
        for (int mt = 0; mt < 2; ++mt) {
            float* orow = out + ((long)t * 32 + mt * 16 + q * 4) * 960 + lr;
            #pragma unroll
            for (int p2 = 0; p2 < 2; ++p2)
                #pragma unroll
                for (int j = 0; j < 4; ++j) {         // 128B line per (row,pair)
                    orow[j * 960 + (wv * 4 + 2 * p2) * 16]     = acc[mt][2 * p2][j];
                    orow[j * 960 + (wv * 4 + 2 * p2 + 1) * 16] = acc[mt][2 * p2 + 1][j];
                }
        }
    }
}

// ---------------- type 1: 128x1o, K=128, R=3, 16-row tiles ----------------
__device__ void do_t1(const float* __restrict__ x, const u16t* __restrict__ wb,
                      float* __restrict__ out, char* sA,
                      int t0, int ts, int ntiles, int tid) {
    const int row = tid >> 4, jj = tid & 15;          // 16 rows x 16 thr, 96B/thr
    const int lane = tid & 63, wv = tid >> 6, lr = lane & 15, q = lane >> 4;
    const int swr = (row & 7) << 4, swl = (lr & 7) << 4;
    const float* gp = x + (long)row * 960 + 256 + jj * 24;

    f32x4 g[6];
    {   const float* p = gp + (long)t0 * 16 * 960;
        #pragma unroll
        for (int i = 0; i < 6; ++i) g[i] = *(const f32x4*)(p + 4 * i); }
    __builtin_amdgcn_sched_barrier(0);

    int w = 0;
    for (int t = t0; t < ntiles; t += ts, w ^= 1) {
        char* buf = sA + w * 12288;
        #pragma unroll
        for (int r = 0; r < 3; ++r) {                 // affine de-interleave
            bf16x8 v;
            #pragma unroll
            for (int kk = 0; kk < 8; ++kk) {
                int c = 3 * kk + r;
                v[kk] = f2bf(g[c >> 2][c & 3]);
            }
            *(bf16x8*)(buf + r * 4096 + row * 256 + ((jj * 16) ^ swr)) = v;
        }
        if (t + ts < ntiles) {
            const float* p = gp + (long)(t + ts) * 16 * 960;
            #pragma unroll
            for (int i = 0; i < 6; ++i) g[i] = *(const f32x4*)(p + 4 * i);
        }
        __builtin_amdgcn_sched_barrier(0);
        asm volatile("s_waitcnt lgkmcnt(0)" ::: "memory");
        __builtin_amdgcn_s_barrier();
        __builtin_amdgcn_sched_barrier(0);

        f32x4 acc[2][3] = {};
        const u16t* wq = wb + lr * 128 + q * 8;
        #pragma unroll
        for (int ks = 0; ks < 4; ++ks) {
            bf16x8 b[2];
            b[0] = *(const bf16x8*)(wq + (wv * 2 + 0) * 2048 + ks * 32);
            b[1] = *(const bf16x8*)(wq + (wv * 2 + 1) * 2048 + ks * 32);
            #pragma unroll
            for (int r = 0; r < 3; ++r) {
                bf16x8 a = *(const bf16x8*)(buf + r * 4096 + lr * 256 +
                                            ((ks * 64 + q * 16) ^ swl));
                acc[0][r] = mfma16(a, b[0], acc[0][r]);
                acc[1][r] = mfma16(a, b[1], acc[1][r]);
            }
        }
        float* orow = out + ((long)t * 16 + q * 4) * 960 + 256 + 3 * lr;
        #pragma unroll
        for (int j = 0; j < 4; ++j)                   // 384B contig span/row
            #pragma unroll
            for (int n = 0; n < 2; ++n)
                #pragma unroll
                for (int r = 0; r < 3; ++r)
                    orow[j * 960 + 48 * (wv * 2 + n) + r] = acc[n][r][j];
    }
}

// ---------------- type 2: 64x2e, K=64, R=5, 16-row tiles ----------------
__device__ void do_t2(const float* __restrict__ x, const u16t* __restrict__ wb,
                      float* __restrict__ out, char* sA,
                      int t0, int ts, int ntiles, int tid) {
    const int row = tid >> 4, jj = tid & 15;          // 16 rows x 16 thr, 80B/thr
    const int lane = tid & 63, wv = tid >> 6, lr = lane & 15, q = lane >> 4;
    const int swr = (row & 7) << 4, swl = (lr & 7) << 4;
    const float* gp = x + (long)row * 960 + 640 + jj * 20;

    f32x4 g[5];
    {   const float* p = gp + (long)t0 * 16 * 960;
        #pragma unroll
        for (int i = 0; i < 5; ++i) g[i] = *(const f32x4*)(p + 4 * i); }
    __builtin_amdgcn_sched_barrier(0);

    int w = 0;
    for (int t = t0; t < ntiles; t += ts, w ^= 1) {
        char* buf = sA + w * 10240;
        #pragma unroll
        for (int r = 0; r < 5; ++r) {
            bf16x4 v;
            #pragma unroll
            for (int kk = 0; kk < 4; ++kk) {
                int c = 5 * kk + r;
                v[kk] = f2bf(g[c >> 2][c & 3]);
            }
            *(bf16x4*)(buf + r * 2048 + row * 128 + ((jj * 8) ^ swr)) = v;
        }
        if (t + ts < ntiles) {
            const float* p = gp + (long)(t + ts) * 16 * 960;
            #pragma unroll
            for (int i = 0; i < 5; ++i) g[i] = *(const f32x4*)(p + 4 * i);
        }
        __builtin_amdgcn_sched_barrier(0);
        asm volatile("s_waitcnt lgkmcnt(0)" ::: "memory");
        __builtin_amdgcn_s_barrier();
        __builtin_amdgcn_sched_barrier(0);

        if (wv < 2) {                                 // 2 nt-pairs over 2 waves
            f32x4 acc[2][5] = {};
            const u16t* wq = wb + lr * 64 + q * 8;
            #pragma unroll
            for (int ks = 0; ks < 2; ++ks) {
                bf16x8 b[2];
                b[0] = *(const bf16x8*)(wq + (wv * 2 + 0) * 1024 + ks * 32);
                b[1] = *(const bf16x8*)(wq + (wv * 2 + 1) * 1024 + ks * 32);
                #pragma unroll
                for (int r = 0; r < 5; ++r) {
                    bf16x8 a = *(const bf16x8*)(buf + r * 2048 + lr * 128 +
                                                ((ks * 64 + q * 16) ^ swl));
                    acc[0][r] = mfma16(a, b[0], acc[0][r]);
                    acc[1][r] = mfma16(a, b[1], acc[1][r]);
                }
            }
            float* orow = out + ((long)t * 16 + q * 4) * 960 + 640 + 5 * lr;
            #pragma unroll
            for (int j = 0; j < 4; ++j)               // 640B contig span/row
                #pragma unroll
                for (int n = 0; n < 2; ++n)
                    #pragma unroll
                    for (int r = 0; r < 5; ++r)
                        orow[j * 960 + 80 * (wv * 2 + n) + r] = acc[n][r][j];
        }
    }
}

// type-interleaved dispatch, WG count per type proportional to its HBM bytes
__global__ __launch_bounds__(256, 4)
void fused_linear(const float* __restrict__ x, const u16t* __restrict__ wt,
                  float* __restrict__ out, int n16) {
    __shared__ __align__(16) char sA[32768];
    const int tid = threadIdx.x;
    const int s = (int)(blockIdx.x % 48);
    const int grp = (int)(blockIdx.x / 48);
    const int ngrp = (int)(gridDim.x / 48);
    if (s < 13)
        do_t0(x, wt, out, sA, grp * 13 + s, ngrp * 13, n16 / 2, tid);
    else if (s < 32)
        do_t1(x, wt + 65536, out, sA, grp * 19 + (s - 13), ngrp * 19, n16, tid);
    else
        do_t2(x, wt + 81920, out, sA, grp * 16 + (s - 32), ngrp * 16, n16, tid);
}

extern "C" void kernel_launch(void* const* d_in, const int* in_sizes, int n_in,
                              void* d_out, int out_size, void* d_ws, size_t ws_size,
                              hipStream_t stream) {
    const float* x  = (const float*)d_in[0];
    const float* w0 = (const float*)d_in[1];
    const float* w1 = (const float*)d_in[2];
    const float* w2 = (const float*)d_in[3];
    float* out = (float*)d_out;
    u16t* wt = (u16t*)d_ws;   // 86016 u16 = 168 KB

    const int N = in_sizes[0] / 960;

    convert_w<<<256, 256, 0, stream>>>(w0, wt,         256, 0.0625f);
    convert_w<<< 64, 256, 0, stream>>>(w1, wt + 65536, 128, 0.08838834764831845f);
    convert_w<<< 16, 256, 0, stream>>>(w2, wt + 81920,  64, 0.125f);

    fused_linear<<<64 * 48, 256, 0, stream>>>(x, wt, out, N / 16);
}